// Round 9
// baseline (238.200 us; speedup 1.0000x reference)
//
#include <hip/hip_runtime.h>
#include <hip/hip_bf16.h>

#define NROWS 131072
#define DK    1024
#define CCLS  21
#define CTF   84
#define NCOL  105          // 21 + 84
#define NCT   7            // 112 padded cols / 16
#define BM    128          // 4 waves x 32 rows
#define BKF   64           // f32 per slab (256 B per row per slab)
#define NSLAB (DK / BKF)   // 16

#define PROBE_BLOCKS 2048
#define PROBE_THREADS 256

typedef __attribute__((ext_vector_type(4))) float f32x4;
typedef __attribute__((ext_vector_type(8))) short bf16x8;

typedef const __attribute__((address_space(1))) void GV;
typedef __attribute__((address_space(3))) void LV;

__device__ __forceinline__ unsigned short f2bf_rne(float x) {
    union { float f; unsigned u; } v; v.f = x;
    unsigned r = v.u + 0x7fffu + ((v.u >> 16) & 1u);
    return (unsigned short)(r >> 16);
}

__device__ __forceinline__ unsigned pack2(float lo, float hi) {
    union { float f; unsigned u; } a, b; a.f = lo; b.f = hi;
    return ((a.u + 0x8000u) >> 16) | ((b.u + 0x8000u) & 0xffff0000u);
}

__device__ __forceinline__ bf16x8 cvt8v(const f32x4 lo, const f32x4 hi) {
    union { unsigned u[4]; bf16x8 v; } r;
    r.u[0] = pack2(lo[0], lo[1]);
    r.u[1] = pack2(lo[2], lo[3]);
    r.u[2] = pack2(hi[0], hi[1]);
    r.u[3] = pack2(hi[2], hi[3]);
    return r.v;
}

// Pack [W_cls | W_tf | zero-pad] into bf16 MFMA B-fragment order (verified):
// element ((kt*NCT+ct)*64+lane)*8 + j = B[k][col],
// col = ct*16 + (lane&15), k = kt*32 + (lane>>4)*8 + j
__global__ void pack_B_kernel(const float* __restrict__ Wc,
                              const float* __restrict__ Wt,
                              unsigned short* __restrict__ Bp) {
    const int frag = blockIdx.x;           // 224 total
    const int kt = frag / NCT, ct = frag % NCT;
    const int lane = threadIdx.x;          // 64
    const int col = ct * 16 + (lane & 15);
    const int k0  = kt * 32 + ((lane >> 4) << 3);
    bf16x8 o;
#pragma unroll
    for (int j = 0; j < 8; ++j) {
        const int k = k0 + j;
        float v = 0.0f;
        if (col < CCLS)      v = Wc[k * CCLS + col];
        else if (col < NCOL) v = Wt[k * CTF + (col - CCLS)];
        o[j] = (short)f2bf_rne(v);
    }
    *reinterpret_cast<bf16x8*>(Bp + ((size_t)frag * 64 + lane) * 8) = o;
}

// Measured-best GEMM (R4/R8, 153.1-153.3 us) — byte-identical this round.
__global__ __launch_bounds__(256, 2)
void roi_gemm_kernel(const float* __restrict__ F,
                     const unsigned short* __restrict__ Bp,
                     const float* __restrict__ bcls,
                     const float* __restrict__ btf,
                     float* __restrict__ out) {
    // [buf][wave][row 0..31][chunk16B 0..15] = 64 KiB
    __shared__ float Alds[2][4][32][BKF];

    const int t    = threadIdx.x;
    const int wave = t >> 6;
    const int lane = t & 63;
    const int fr   = lane & 15;      // A/C row-in-tile, B col
    const int fq   = lane >> 4;      // 0..3
    const int sw   = fr & 7;         // read-side XOR swizzle

    const long rw = (long)blockIdx.x * BM + wave * 32;

    const float* srcE = F + (size_t)(rw + fq) * DK + ((fr ^ fq) << 2);
    const float* srcO = F + (size_t)(rw + fq) * DK + ((fr ^ (fq + 4)) << 2);
    const unsigned short* bb = Bp + (size_t)lane * 8;

    f32x4 acc[2][NCT];
#pragma unroll
    for (int a = 0; a < 2; ++a)
#pragma unroll
        for (int b = 0; b < NCT; ++b)
            acc[a][b] = (f32x4){0.f, 0.f, 0.f, 0.f};

#define STAGE(BUF, S) do {                                                   \
    const float* _e = srcE + (size_t)(S) * BKF;                              \
    const float* _o = srcO + (size_t)(S) * BKF;                              \
    _Pragma("unroll")                                                        \
    for (int q = 0; q < 8; ++q) {                                            \
        const float* g = ((q & 1) ? _o : _e) + (size_t)q * 4 * DK;           \
        __builtin_amdgcn_global_load_lds((GV*)g,                             \
            (LV*)&Alds[BUF][wave][q * 4][0], 16, 0, 0);                      \
    }                                                                        \
} while (0)

    STAGE(0, 0);   // prologue: 8 DMA outstanding

    for (int s = 0; s < NSLAB; ++s) {
        const int buf = s & 1;

        __builtin_amdgcn_sched_barrier(0);
        bf16x8 bf[2][NCT];
#pragma unroll
        for (int kt = 0; kt < 2; ++kt)
#pragma unroll
            for (int ct = 0; ct < NCT; ++ct)
                bf[kt][ct] = *reinterpret_cast<const bf16x8*>(
                    bb + ((size_t)((s * 2 + kt) * NCT + ct) * 512));
        __builtin_amdgcn_sched_barrier(0);

        if (s + 1 < NSLAB) {
            STAGE((s + 1) & 1, s + 1);
            __builtin_amdgcn_sched_barrier(0);
            asm volatile("s_waitcnt vmcnt(8)" ::: "memory");
        } else {
            asm volatile("s_waitcnt vmcnt(0)" ::: "memory");
        }
        __builtin_amdgcn_sched_barrier(0);

#pragma unroll
        for (int kt = 0; kt < 2; ++kt) {
            bf16x8 af[2];
#pragma unroll
            for (int rt = 0; rt < 2; ++rt) {
                const float* lpr = &Alds[buf][wave][rt * 16 + fr][0];
                const int c0 = kt * 8 + fq * 2;
                const f32x4 lo = *reinterpret_cast<const f32x4*>(
                    lpr + (((c0 + 0) ^ sw) << 2));
                const f32x4 hi = *reinterpret_cast<const f32x4*>(
                    lpr + (((c0 + 1) ^ sw) << 2));
                af[rt] = cvt8v(lo, hi);
            }
#pragma unroll
            for (int ct = 0; ct < NCT; ++ct) {
                acc[0][ct] = __builtin_amdgcn_mfma_f32_16x16x32_bf16(
                    af[0], bf[kt][ct], acc[0][ct], 0, 0, 0);
                acc[1][ct] = __builtin_amdgcn_mfma_f32_16x16x32_bf16(
                    af[1], bf[kt][ct], acc[1][ct], 0, 0, 0);
            }
        }
    }
#undef STAGE

    float* out_tf = out + (size_t)NROWS * CCLS;
#pragma unroll
    for (int rt = 0; rt < 2; ++rt) {
        const long rbase = rw + rt * 16 + (fq << 2);
#pragma unroll
        for (int ct = 0; ct < NCT; ++ct) {
            const int col = ct * 16 + fr;
            if (col >= NCOL) continue;
            const float bias = (col < CCLS) ? bcls[col] : btf[col - CCLS];
#pragma unroll
            for (int j = 0; j < 4; ++j) {
                const long row = rbase + j;
                const float v = acc[rt][ct][j] + bias;
                if (col < CCLS) out[row * CCLS + col] = v;
                else            out_tf[row * CTF + (col - CCLS)] = v;
            }
        }
    }
}

// MEASUREMENT PROBE (this round only): BabelStream-style pure-read sweep of
// F (537 MB) at max occupancy. dur_us minus the GEMM's known 153 us gives
// the chip's pure-read rate — the external-reference ceiling check (rule 10).
// Sink is write-only scratch in d_ws; deterministic per-wave sums.
__global__ __launch_bounds__(256)
void read_probe_kernel(const float* __restrict__ F, float* __restrict__ sink) {
    const size_t tid = (size_t)blockIdx.x * PROBE_THREADS + threadIdx.x;
    const size_t nth = (size_t)PROBE_BLOCKS * PROBE_THREADS;
    const f32x4* p = reinterpret_cast<const f32x4*>(F);
    const size_t nvec = (size_t)NROWS * DK / 4;   // 33,554,432 -> 64 iters
    f32x4 s = (f32x4){0.f, 0.f, 0.f, 0.f};
    for (size_t i = tid; i < nvec; i += nth)
        s += p[i];
    float r = s[0] + s[1] + s[2] + s[3];
#pragma unroll
    for (int o = 32; o > 0; o >>= 1) r += __shfl_down(r, o, 64);
    if ((threadIdx.x & 63) == 0)
        sink[blockIdx.x * (PROBE_THREADS / 64) + (threadIdx.x >> 6)] = r;
}

extern "C" void kernel_launch(void* const* d_in, const int* in_sizes, int n_in,
                              void* d_out, int out_size, void* d_ws, size_t ws_size,
                              hipStream_t stream) {
    const float* F  = (const float*)d_in[0];
    const float* Wc = (const float*)d_in[1];
    const float* bc = (const float*)d_in[2];
    const float* Wt = (const float*)d_in[3];
    const float* bt = (const float*)d_in[4];
    unsigned short* Bp = (unsigned short*)d_ws;   // 229,376 B

    // probe sink: 32 KB of scratch; prefer past Bp, overlap harmless anyway
    // (probe runs after GEMM consumed Bp; pack_B rewrites Bp every call)
    float* sink = (ws_size >= 229376 + 32768)
                      ? (float*)((char*)d_ws + 229376)
                      : (float*)d_ws;

    pack_B_kernel<<<NCT * (DK / 32), 64, 0, stream>>>(Wc, Wt, Bp);
    roi_gemm_kernel<<<NROWS / BM, 256, 0, stream>>>(F, Bp, bc, bt,
                                                    (float*)d_out);
    read_probe_kernel<<<PROBE_BLOCKS, PROBE_THREADS, 0, stream>>>(F, sink);
}

// Round 10
// 163.136 us; speedup vs baseline: 1.4601x; 1.4601x over previous
//
#include <hip/hip_runtime.h>
#include <hip/hip_bf16.h>

#define NROWS 131072
#define DK    1024
#define CCLS  21
#define CTF   84
#define NCOL  105          // 21 + 84
#define NCT   7            // 112 padded cols / 16
#define BM    32           // rows per block tile (full-K staged)

typedef __attribute__((ext_vector_type(4))) float f32x4;
typedef __attribute__((ext_vector_type(8))) short bf16x8;
typedef __attribute__((ext_vector_type(2))) unsigned int u32x2;

__device__ __forceinline__ unsigned short f2bf_rne(float x) {
    union { float f; unsigned u; } v; v.f = x;
    unsigned r = v.u + 0x7fffu + ((v.u >> 16) & 1u);
    return (unsigned short)(r >> 16);
}

__device__ __forceinline__ unsigned pack2(float lo, float hi) {
    union { float f; unsigned u; } a, b; a.f = lo; b.f = hi;
    return ((a.u + 0x8000u) >> 16) | ((b.u + 0x8000u) & 0xffff0000u);
}

// Pack [W_cls | W_tf | zero-pad] into bf16 MFMA B-fragment order (verified):
// element ((kt*NCT+ct)*64+lane)*8 + j = B[k][col],
// col = ct*16 + (lane&15), k = kt*32 + (lane>>4)*8 + j
__global__ void pack_B_kernel(const float* __restrict__ Wc,
                              const float* __restrict__ Wt,
                              unsigned short* __restrict__ Bp) {
    const int frag = blockIdx.x;           // 224 total
    const int kt = frag / NCT, ct = frag % NCT;
    const int lane = threadIdx.x;          // 64
    const int col = ct * 16 + (lane & 15);
    const int k0  = kt * 32 + ((lane >> 4) << 3);
    bf16x8 o;
#pragma unroll
    for (int j = 0; j < 8; ++j) {
        const int k = k0 + j;
        float v = 0.0f;
        if (col < CCLS)      v = Wc[k * CCLS + col];
        else if (col < NCOL) v = Wt[k * CTF + (col - CCLS)];
        o[j] = (short)f2bf_rne(v);
    }
    *reinterpret_cast<bf16x8*>(Bp + ((size_t)frag * 64 + lane) * 8) = o;
}

// Full-row GEMM: block = 32 rows x full K=1024. Stage reads are
// probe-pattern (1KB contiguous per wave instruction, full 4KB per row,
// page-dense). bf16 tile in 64KB XOR-swizzled LDS; MFMA K-split across
// 4 waves (8 k-tiles each); LDS partial reduce (reuses staging buffer).
__global__ __launch_bounds__(256, 2)
void roi_gemm_kernel(const float* __restrict__ F,
                     const unsigned short* __restrict__ Bp,
                     const float* __restrict__ bcls,
                     const float* __restrict__ btf,
                     float* __restrict__ out) {
    __shared__ __align__(16) unsigned char smem[65536];  // 64 KiB

    const int t    = threadIdx.x;
    const int wave = t >> 6;
    const int lane = t & 63;
    const int fr   = lane & 15;
    const int fq   = lane >> 4;
    const long rw  = (long)blockIdx.x * BM;

    // ---- stage: wave w stages local rows w*8..w*8+7, FULL rows.
    // One instruction = 64 lanes x f32x4 = 1 KB contiguous (probe pattern);
    // q=0..3 back-to-back covers the whole 4 KB row.
    // LDS tile[32][1024] bf16, chunk16 index swizzled: ch ^= (row & 7).
    {
        const int r0 = wave * 8;
#pragma unroll
        for (int p = 0; p < 4; ++p) {
            f32x4 v[2][4];
#pragma unroll
            for (int e = 0; e < 2; ++e) {
                const int R = r0 + p * 2 + e;
                const float* src = F + (size_t)(rw + R) * DK + lane * 4;
#pragma unroll
                for (int q = 0; q < 4; ++q)
                    v[e][q] = *reinterpret_cast<const f32x4*>(src + q * 256);
            }
#pragma unroll
            for (int e = 0; e < 2; ++e) {
                const int R = r0 + p * 2 + e;
#pragma unroll
                for (int q = 0; q < 4; ++q) {
                    u32x2 d;
                    d[0] = pack2(v[e][q][0], v[e][q][1]);
                    d[1] = pack2(v[e][q][2], v[e][q][3]);
                    const int ch = (q * 32 + (lane >> 1)) ^ (R & 7);
                    *reinterpret_cast<u32x2*>(
                        smem + R * 2048 + ch * 16 + (lane & 1) * 8) = d;
                }
            }
        }
    }
    __syncthreads();

    // ---- MFMA: K-split across waves — wave w handles k-tiles w*8..w*8+7
    f32x4 acc[2][NCT];
#pragma unroll
    for (int a = 0; a < 2; ++a)
#pragma unroll
        for (int b = 0; b < NCT; ++b)
            acc[a][b] = (f32x4){0.f, 0.f, 0.f, 0.f};

    const unsigned short* bb = Bp + (size_t)lane * 8;
    const int w8 = wave * 8;

    bf16x8 bfr[2][NCT];
#pragma unroll
    for (int ct = 0; ct < NCT; ++ct)
        bfr[0][ct] = *reinterpret_cast<const bf16x8*>(
            bb + ((size_t)(w8 * NCT + ct) * 512));

#pragma unroll
    for (int j = 0; j < 8; ++j) {
        const int cur = j & 1;
        if (j + 1 < 8) {
#pragma unroll
            for (int ct = 0; ct < NCT; ++ct)
                bfr[cur ^ 1][ct] = *reinterpret_cast<const bf16x8*>(
                    bb + ((size_t)((w8 + j + 1) * NCT + ct) * 512));
        }
        const int ktg = w8 + j;
        bf16x8 a[2];
#pragma unroll
        for (int rt = 0; rt < 2; ++rt) {
            const int R = rt * 16 + fr;
            const int ch = (ktg * 4 + fq) ^ (R & 7);
            a[rt] = *reinterpret_cast<const bf16x8*>(smem + R * 2048 + ch * 16);
        }
#pragma unroll
        for (int ct = 0; ct < NCT; ++ct) {
            acc[0][ct] = __builtin_amdgcn_mfma_f32_16x16x32_bf16(
                a[0], bfr[cur][ct], acc[0][ct], 0, 0, 0);
            acc[1][ct] = __builtin_amdgcn_mfma_f32_16x16x32_bf16(
                a[1], bfr[cur][ct], acc[1][ct], 0, 0, 0);
        }
    }

    // ---- cross-wave K reduction through LDS (reuse staging buffer)
    __syncthreads();   // all waves done reading the tile
#pragma unroll
    for (int rt = 0; rt < 2; ++rt)
#pragma unroll
        for (int ct = 0; ct < NCT; ++ct)
            *reinterpret_cast<f32x4*>(
                smem + (size_t)(wave * 14 + rt * 7 + ct) * 1024 + lane * 16) =
                acc[rt][ct];
    __syncthreads();

    // ---- reduce 4 partials + bias + store. Slot s=rt*7+ct; f32 index
    // within slot = t (lane = t>>2, elem j = t&3).
    const float* sf = reinterpret_cast<const float*>(smem);
    float* out_tf = out + (size_t)NROWS * CCLS;
    const int rl = t >> 2;
    const int rj = t & 3;
#pragma unroll
    for (int s = 0; s < 14; ++s) {
        const int rt = s / 7, ct = s % 7;
        const int col = ct * 16 + (rl & 15);
        if (col >= NCOL) continue;
        const float v = sf[0 * 3584 + s * 256 + t] +
                        sf[1 * 3584 + s * 256 + t] +
                        sf[2 * 3584 + s * 256 + t] +
                        sf[3 * 3584 + s * 256 + t] +
                        ((col < CCLS) ? bcls[col] : btf[col - CCLS]);
        const long row = rw + rt * 16 + ((rl >> 4) << 2) + rj;
        if (col < CCLS) out[row * CCLS + col] = v;
        else            out_tf[row * CTF + (col - CCLS)] = v;
    }
}

extern "C" void kernel_launch(void* const* d_in, const int* in_sizes, int n_in,
                              void* d_out, int out_size, void* d_ws, size_t ws_size,
                              hipStream_t stream) {
    const float* F  = (const float*)d_in[0];
    const float* Wc = (const float*)d_in[1];
    const float* bc = (const float*)d_in[2];
    const float* Wt = (const float*)d_in[3];
    const float* bt = (const float*)d_in[4];
    unsigned short* Bp = (unsigned short*)d_ws;   // 229,376 B

    pack_B_kernel<<<NCT * (DK / 32), 64, 0, stream>>>(Wc, Wt, Bp);
    roi_gemm_kernel<<<NROWS / BM, 256, 0, stream>>>(F, Bp, bc, bt,
                                                    (float*)d_out);
}